// Round 1
// baseline (382.219 us; speedup 1.0000x reference)
//
#include <hip/hip_runtime.h>

// Problem constants (from reference)
#define NN 4096
#define CC 128
#define II 9
#define DD 9
#define EE 10
#define PP3 23
#define PP2 5
#define PP1 3
// symmetric monomial counts over 9 vars
#define F3 165   // i<=j<=k
#define F2 45    // i<=j
#define F1 9
#define FTOT (F3 + F2 + F1)  // 219
#define ROW 12               // padded LDS row (floats), 48B => 16B aligned

// workspace layout (bytes)
#define SU3_ELEMS (F3 * PP3 * DD)              // 34155 floats
#define SU2_ELEMS (F2 * PP2 * DD)              // 2025 floats
#define SU3_OFF 0
#define SU2_OFF (SU3_ELEMS * 4)                // 136620
#define CUR_OFF (SU2_OFF + SU2_ELEMS * 4)      // 144720
#define LIST_OFF (CUR_OFF + 16 * 4)            // 144784

__global__ void zero_cursors_kernel(int* cursors) {
    if (threadIdx.x < 16) cursors[threadIdx.x] = 0;
}

__global__ void bucket_kernel(const int* __restrict__ indices,
                              int* __restrict__ cursors,
                              int* __restrict__ lists) {
    int b = blockIdx.x * blockDim.x + threadIdx.x;
    if (b < NN) {
        int e = indices[b];
        int slot = atomicAdd(&cursors[e], 1);
        lists[e * NN + slot] = b;
    }
}

// Symmetrize u3 over (i,j,k) and u2 over (i,j) into monomial-indexed tensors.
// su3[(t*PP3+p)*9+d] = sum over distinct perms (a,b,c) of sorted triple t of u3[d,a,b,c,p]
// su2[(t*PP2+p)*9+d] = sum over distinct perms of pair
__global__ void sym_u_kernel(const float* __restrict__ u3,
                             const float* __restrict__ u2,
                             float* __restrict__ su3,
                             float* __restrict__ su2) {
    int gid = blockIdx.x * blockDim.x + threadIdx.x;
    if (gid < F3 * PP3) {
        int t = gid / PP3, p = gid % PP3;
        // recover (i<=j<=k) from canonical enumeration
        int I0 = 0, J0 = 0, K0 = 0, tt = 0;
        for (int i = 0; i < 9; i++)
            for (int j = i; j < 9; j++)
                for (int k = j; k < 9; k++) {
                    if (tt == t) { I0 = i; J0 = j; K0 = k; }
                    tt++;
                }
        int a[3] = {I0, J0, K0};
        const int ord[6][3] = {{0,1,2},{0,2,1},{1,0,2},{1,2,0},{2,0,1},{2,1,0}};
        int codes[6], pi[6], pj[6], pk[6];
        int np = 0;
        for (int q = 0; q < 6; q++) {
            int ii = a[ord[q][0]], jj = a[ord[q][1]], kk = a[ord[q][2]];
            int code = (ii * 9 + jj) * 9 + kk;
            bool seen = false;
            for (int r = 0; r < np; r++) if (codes[r] == code) seen = true;
            if (!seen) { codes[np] = code; pi[np] = ii; pj[np] = jj; pk[np] = kk; np++; }
        }
        for (int d = 0; d < 9; d++) {
            float s = 0.f;
            for (int q = 0; q < np; q++)
                s += u3[((((d * 9 + pi[q]) * 9 + pj[q]) * 9 + pk[q]) * PP3) + p];
            su3[(t * PP3 + p) * 9 + d] = s;
        }
    } else if (gid < F3 * PP3 + F2 * PP2) {
        int r = gid - F3 * PP3;
        int t = r / PP2, p = r % PP2;
        int I0 = 0, J0 = 0, tt = 0;
        for (int i = 0; i < 9; i++)
            for (int j = i; j < 9; j++) {
                if (tt == t) { I0 = i; J0 = j; }
                tt++;
            }
        for (int d = 0; d < 9; d++) {
            float s = u2[(((d * 9 + I0) * 9 + J0) * PP2) + p];
            if (I0 != J0) s += u2[(((d * 9 + J0) * 9 + I0) * PP2) + p];
            su2[(t * PP2 + p) * 9 + d] = s;
        }
    }
}

// Main: one block per (c, e). Build W[e,c][219][9] in LDS, then each thread
// evaluates the cubic form for its nodes via fused monomial+matvec loop.
__global__ __launch_bounds__(256) void symcon_main_kernel(
    const float* __restrict__ x,
    const float* __restrict__ u1,
    const float* __restrict__ w3,
    const float* __restrict__ w2,
    const float* __restrict__ w1,
    const float* __restrict__ su3,
    const float* __restrict__ su2,
    const int* __restrict__ cursors,
    const int* __restrict__ lists,
    float* __restrict__ out)
{
    const int c = blockIdx.x;
    const int e = blockIdx.y;
    __shared__ __align__(16) float sW[FTOT * ROW];

    // prologue: W[f][d] for this (e,c)
    for (int idx = threadIdx.x; idx < FTOT * 9; idx += blockDim.x) {
        int f = idx / 9, d = idx % 9;
        float v = 0.f;
        if (f < F3) {
            #pragma unroll 1
            for (int p = 0; p < PP3; p++)
                v += su3[(f * PP3 + p) * 9 + d] * w3[(e * PP3 + p) * CC + c];
        } else if (f < F3 + F2) {
            int t = f - F3;
            for (int p = 0; p < PP2; p++)
                v += su2[(t * PP2 + p) * 9 + d] * w2[(e * PP2 + p) * CC + c];
        } else {
            int i = f - F3 - F2;
            for (int p = 0; p < PP1; p++)
                v += u1[(d * 9 + i) * PP1 + p] * w1[(e * PP1 + p) * CC + c];
        }
        sW[f * ROW + d] = v;
    }
    __syncthreads();

    int cnt = cursors[e];
    for (int n = threadIdx.x; n < cnt; n += blockDim.x) {
        int b = lists[e * NN + n];
        const float* xr = x + ((size_t)b * CC + c) * II;
        float xv[9];
        #pragma unroll
        for (int q = 0; q < 9; q++) xv[q] = xr[q];

        float acc[9];
        #pragma unroll
        for (int d = 0; d < 9; d++) acc[d] = 0.f;

        int f = 0;
        // degree 3: canonical i<=j<=k
        for (int i = 0; i < 9; i++) {
            for (int j = i; j < 9; j++) {
                float xij = xv[i] * xv[j];
                for (int k = j; k < 9; k++) {
                    float m = xij * xv[k];
                    const float4* w4 = reinterpret_cast<const float4*>(&sW[f * ROW]);
                    float4 wa = w4[0];
                    float4 wb = w4[1];
                    float w8 = sW[f * ROW + 8];
                    acc[0] += wa.x * m; acc[1] += wa.y * m; acc[2] += wa.z * m; acc[3] += wa.w * m;
                    acc[4] += wb.x * m; acc[5] += wb.y * m; acc[6] += wb.z * m; acc[7] += wb.w * m;
                    acc[8] += w8 * m;
                    f++;
                }
            }
        }
        // degree 2: canonical i<=j
        for (int i = 0; i < 9; i++) {
            for (int j = i; j < 9; j++) {
                float m = xv[i] * xv[j];
                const float4* w4 = reinterpret_cast<const float4*>(&sW[f * ROW]);
                float4 wa = w4[0];
                float4 wb = w4[1];
                float w8 = sW[f * ROW + 8];
                acc[0] += wa.x * m; acc[1] += wa.y * m; acc[2] += wa.z * m; acc[3] += wa.w * m;
                acc[4] += wb.x * m; acc[5] += wb.y * m; acc[6] += wb.z * m; acc[7] += wb.w * m;
                acc[8] += w8 * m;
                f++;
            }
        }
        // degree 1
        for (int i = 0; i < 9; i++) {
            float m = xv[i];
            const float4* w4 = reinterpret_cast<const float4*>(&sW[f * ROW]);
            float4 wa = w4[0];
            float4 wb = w4[1];
            float w8 = sW[f * ROW + 8];
            acc[0] += wa.x * m; acc[1] += wa.y * m; acc[2] += wa.z * m; acc[3] += wa.w * m;
            acc[4] += wb.x * m; acc[5] += wb.y * m; acc[6] += wb.z * m; acc[7] += wb.w * m;
            acc[8] += w8 * m;
            f++;
        }

        float* op = out + ((size_t)b * CC + c) * DD;
        #pragma unroll
        for (int d = 0; d < 9; d++) op[d] = acc[d];
    }
}

extern "C" void kernel_launch(void* const* d_in, const int* in_sizes, int n_in,
                              void* d_out, int out_size, void* d_ws, size_t ws_size,
                              hipStream_t stream) {
    const float* x   = (const float*)d_in[0];
    const int* indices = (const int*)d_in[1];
    const float* u3  = (const float*)d_in[2];
    const float* u2  = (const float*)d_in[3];
    const float* u1  = (const float*)d_in[4];
    const float* w3  = (const float*)d_in[5];
    const float* w2  = (const float*)d_in[6];
    const float* w1  = (const float*)d_in[7];
    float* out = (float*)d_out;

    char* ws = (char*)d_ws;
    float* su3 = (float*)(ws + SU3_OFF);
    float* su2 = (float*)(ws + SU2_OFF);
    int* cursors = (int*)(ws + CUR_OFF);
    int* lists = (int*)(ws + LIST_OFF);

    hipLaunchKernelGGL(zero_cursors_kernel, dim3(1), dim3(64), 0, stream, cursors);
    hipLaunchKernelGGL(bucket_kernel, dim3((NN + 255) / 256), dim3(256), 0, stream,
                       indices, cursors, lists);
    hipLaunchKernelGGL(sym_u_kernel, dim3((F3 * PP3 + F2 * PP2 + 255) / 256), dim3(256),
                       0, stream, u3, u2, su3, su2);
    hipLaunchKernelGGL(symcon_main_kernel, dim3(CC, EE), dim3(256), 0, stream,
                       x, u1, w3, w2, w1, su3, su2, cursors, lists, out);
}

// Round 2
// 263.354 us; speedup vs baseline: 1.4514x; 1.4514x over previous
//
#include <hip/hip_runtime.h>

// Problem constants (from reference)
#define NN 4096
#define CC 128
#define II 9
#define DD 9
#define EE 10
#define PP3 23
#define PP2 5
#define PP1 3
// symmetric monomial counts over 9 vars
#define F3 165   // i<=j<=k
#define F2 45    // i<=j
#define F1 9
#define FTOT (F3 + F2 + F1)  // 219
#define ROW 12               // padded row (floats), 48B -> float4-aligned
#define WIMG (FTOT * ROW)    // 2628 floats per (e,c) LDS image

// workspace layout (bytes)
#define SU3_ELEMS (F3 * PP3 * DD)              // 34155 floats
#define SU2_ELEMS (F2 * PP2 * DD)              // 2025 floats
#define SU3_OFF 0
#define SU2_OFF (SU3_OFF + SU3_ELEMS * 4)
#define CUR_OFF (SU2_OFF + SU2_ELEMS * 4)
#define LIST_OFF (CUR_OFF + 64)                // 16 ints + pad
#define WG_OFF (LIST_OFF + NN * EE * 4)        // then E*C*WIMG floats (~13.5 MB)

#define SPLIT 2

__global__ void zero_cursors_kernel(int* cursors) {
    if (threadIdx.x < 16) cursors[threadIdx.x] = 0;
}

// Deterministic bucketing: rank of node b within its species = #earlier nodes
// of same species. Gives species lists sorted ascending by node id.
__global__ void bucket_rank_kernel(const int* __restrict__ indices,
                                   int* __restrict__ cursors,
                                   int* __restrict__ lists) {
    int b = blockIdx.x * blockDim.x + threadIdx.x;
    if (b < NN) {
        int e = indices[b];
        int rank = 0;
        for (int i = 0; i < b; i++) rank += (indices[i] == e) ? 1 : 0;
        lists[e * NN + rank] = b;
        atomicAdd(&cursors[e], 1);
    }
}

// Symmetrize u3 over (i,j,k) and u2 over (i,j) into monomial-indexed tensors.
__global__ void sym_u_kernel(const float* __restrict__ u3,
                             const float* __restrict__ u2,
                             float* __restrict__ su3,
                             float* __restrict__ su2) {
    int gid = blockIdx.x * blockDim.x + threadIdx.x;
    if (gid < F3 * PP3) {
        int t = gid / PP3, p = gid % PP3;
        int I0 = 0, J0 = 0, K0 = 0, tt = 0;
        for (int i = 0; i < 9; i++)
            for (int j = i; j < 9; j++)
                for (int k = j; k < 9; k++) {
                    if (tt == t) { I0 = i; J0 = j; K0 = k; }
                    tt++;
                }
        int a[3] = {I0, J0, K0};
        const int ord[6][3] = {{0,1,2},{0,2,1},{1,0,2},{1,2,0},{2,0,1},{2,1,0}};
        int codes[6], pi[6], pj[6], pk[6];
        int np = 0;
        for (int q = 0; q < 6; q++) {
            int ii = a[ord[q][0]], jj = a[ord[q][1]], kk = a[ord[q][2]];
            int code = (ii * 9 + jj) * 9 + kk;
            bool seen = false;
            for (int r = 0; r < np; r++) if (codes[r] == code) seen = true;
            if (!seen) { codes[np] = code; pi[np] = ii; pj[np] = jj; pk[np] = kk; np++; }
        }
        for (int d = 0; d < 9; d++) {
            float s = 0.f;
            for (int q = 0; q < np; q++)
                s += u3[((((d * 9 + pi[q]) * 9 + pj[q]) * 9 + pk[q]) * PP3) + p];
            su3[(t * PP3 + p) * 9 + d] = s;
        }
    } else if (gid < F3 * PP3 + F2 * PP2) {
        int r = gid - F3 * PP3;
        int t = r / PP2, p = r % PP2;
        int I0 = 0, J0 = 0, tt = 0;
        for (int i = 0; i < 9; i++)
            for (int j = i; j < 9; j++) {
                if (tt == t) { I0 = i; J0 = j; }
                tt++;
            }
        for (int d = 0; d < 9; d++) {
            float s = u2[(((d * 9 + I0) * 9 + J0) * PP2) + p];
            if (I0 != J0) s += u2[(((d * 9 + J0) * 9 + I0) * PP2) + p];
            su2[(t * PP2 + p) * 9 + d] = s;
        }
    }
}

// Precompute the padded per-(e,c) weight image Wg[e][c][WIMG] so the main
// kernel's prologue is a pure coalesced float4 copy.
__global__ __launch_bounds__(128) void wprep_kernel(
    const float* __restrict__ su3,
    const float* __restrict__ su2,
    const float* __restrict__ u1,
    const float* __restrict__ w3,
    const float* __restrict__ w2,
    const float* __restrict__ w1,
    float* __restrict__ Wg)
{
    const int c = blockIdx.x;
    const int e = blockIdx.y;
    float* dst = Wg + (size_t)(e * CC + c) * WIMG;
    for (int idx = threadIdx.x; idx < WIMG; idx += blockDim.x) {
        int f = idx / ROW, r = idx % ROW;
        float v = 0.f;
        if (r < 9) {
            int d = r;
            if (f < F3) {
                for (int p = 0; p < PP3; p++)
                    v += su3[(f * PP3 + p) * 9 + d] * w3[(e * PP3 + p) * CC + c];
            } else if (f < F3 + F2) {
                int t = f - F3;
                for (int p = 0; p < PP2; p++)
                    v += su2[(t * PP2 + p) * 9 + d] * w2[(e * PP2 + p) * CC + c];
            } else {
                int i = f - F3 - F2;
                for (int p = 0; p < PP1; p++)
                    v += u1[(d * 9 + i) * PP1 + p] * w1[(e * PP1 + p) * CC + c];
            }
        }
        dst[idx] = v;
    }
}

// Main: grid (C, E, SPLIT). Copy W image to LDS, each thread evaluates the
// cubic form for TWO nodes simultaneously (18 FMA per 3 broadcast LDS reads).
__global__ __launch_bounds__(128, 4) void symcon_main_kernel(
    const float* __restrict__ x,
    const float* __restrict__ Wg,
    const int* __restrict__ cursors,
    const int* __restrict__ lists,
    float* __restrict__ out)
{
    const int c = blockIdx.x;
    const int e = blockIdx.y;
    const int s = blockIdx.z;
    __shared__ __align__(16) float sW[WIMG];

    const float4* wsrc = reinterpret_cast<const float4*>(Wg + (size_t)(e * CC + c) * WIMG);
    float4* wdst = reinterpret_cast<float4*>(sW);
    for (int q = threadIdx.x; q < WIMG / 4; q += blockDim.x) wdst[q] = wsrc[q];
    __syncthreads();

    const int cnt = cursors[e];
    const int chunk = (cnt + SPLIT - 1) / SPLIT;
    const int base = s * chunk;
    const int end = (base + chunk < cnt) ? (base + chunk) : cnt;

    for (int n0 = base + (int)threadIdx.x; n0 < end; n0 += 2 * (int)blockDim.x) {
        const int n1 = n0 + (int)blockDim.x;
        const bool has1 = (n1 < end);
        const int b0 = lists[e * NN + n0];
        const int b1 = has1 ? lists[e * NN + n1] : b0;

        float xv0[9], xv1[9];
        const float* xr0 = x + ((size_t)b0 * CC + c) * II;
        const float* xr1 = x + ((size_t)b1 * CC + c) * II;
        #pragma unroll
        for (int q = 0; q < 9; q++) {
            xv0[q] = xr0[q];
            xv1[q] = has1 ? xr1[q] : 0.f;
        }

        float a0[9], a1[9];
        #pragma unroll
        for (int d = 0; d < 9; d++) { a0[d] = 0.f; a1[d] = 0.f; }

        int f = 0;
        // degree 3: canonical i<=j<=k
        #pragma unroll 1
        for (int i = 0; i < 9; i++) {
            #pragma unroll 1
            for (int j = i; j < 9; j++) {
                float p0 = xv0[i] * xv0[j];
                float p1 = xv1[i] * xv1[j];
                for (int k = j; k < 9; k++) {
                    float m0 = p0 * xv0[k];
                    float m1 = p1 * xv1[k];
                    const float4* w4 = reinterpret_cast<const float4*>(&sW[f * ROW]);
                    float4 wa = w4[0];
                    float4 wb = w4[1];
                    float w8 = sW[f * ROW + 8];
                    a0[0] += wa.x * m0; a1[0] += wa.x * m1;
                    a0[1] += wa.y * m0; a1[1] += wa.y * m1;
                    a0[2] += wa.z * m0; a1[2] += wa.z * m1;
                    a0[3] += wa.w * m0; a1[3] += wa.w * m1;
                    a0[4] += wb.x * m0; a1[4] += wb.x * m1;
                    a0[5] += wb.y * m0; a1[5] += wb.y * m1;
                    a0[6] += wb.z * m0; a1[6] += wb.z * m1;
                    a0[7] += wb.w * m0; a1[7] += wb.w * m1;
                    a0[8] += w8 * m0;   a1[8] += w8 * m1;
                    f++;
                }
            }
        }
        // degree 2: canonical i<=j
        #pragma unroll 1
        for (int i = 0; i < 9; i++) {
            for (int j = i; j < 9; j++) {
                float m0 = xv0[i] * xv0[j];
                float m1 = xv1[i] * xv1[j];
                const float4* w4 = reinterpret_cast<const float4*>(&sW[f * ROW]);
                float4 wa = w4[0];
                float4 wb = w4[1];
                float w8 = sW[f * ROW + 8];
                a0[0] += wa.x * m0; a1[0] += wa.x * m1;
                a0[1] += wa.y * m0; a1[1] += wa.y * m1;
                a0[2] += wa.z * m0; a1[2] += wa.z * m1;
                a0[3] += wa.w * m0; a1[3] += wa.w * m1;
                a0[4] += wb.x * m0; a1[4] += wb.x * m1;
                a0[5] += wb.y * m0; a1[5] += wb.y * m1;
                a0[6] += wb.z * m0; a1[6] += wb.z * m1;
                a0[7] += wb.w * m0; a1[7] += wb.w * m1;
                a0[8] += w8 * m0;   a1[8] += w8 * m1;
                f++;
            }
        }
        // degree 1
        for (int i = 0; i < 9; i++) {
            float m0 = xv0[i];
            float m1 = xv1[i];
            const float4* w4 = reinterpret_cast<const float4*>(&sW[f * ROW]);
            float4 wa = w4[0];
            float4 wb = w4[1];
            float w8 = sW[f * ROW + 8];
            a0[0] += wa.x * m0; a1[0] += wa.x * m1;
            a0[1] += wa.y * m0; a1[1] += wa.y * m1;
            a0[2] += wa.z * m0; a1[2] += wa.z * m1;
            a0[3] += wa.w * m0; a1[3] += wa.w * m1;
            a0[4] += wb.x * m0; a1[4] += wb.x * m1;
            a0[5] += wb.y * m0; a1[5] += wb.y * m1;
            a0[6] += wb.z * m0; a1[6] += wb.z * m1;
            a0[7] += wb.w * m0; a1[7] += wb.w * m1;
            a0[8] += w8 * m0;   a1[8] += w8 * m1;
            f++;
        }

        float* op0 = out + ((size_t)b0 * CC + c) * DD;
        #pragma unroll
        for (int d = 0; d < 9; d++) op0[d] = a0[d];
        if (has1) {
            float* op1 = out + ((size_t)b1 * CC + c) * DD;
            #pragma unroll
            for (int d = 0; d < 9; d++) op1[d] = a1[d];
        }
    }
}

extern "C" void kernel_launch(void* const* d_in, const int* in_sizes, int n_in,
                              void* d_out, int out_size, void* d_ws, size_t ws_size,
                              hipStream_t stream) {
    const float* x   = (const float*)d_in[0];
    const int* indices = (const int*)d_in[1];
    const float* u3  = (const float*)d_in[2];
    const float* u2  = (const float*)d_in[3];
    const float* u1  = (const float*)d_in[4];
    const float* w3  = (const float*)d_in[5];
    const float* w2  = (const float*)d_in[6];
    const float* w1  = (const float*)d_in[7];
    float* out = (float*)d_out;

    char* ws = (char*)d_ws;
    float* su3 = (float*)(ws + SU3_OFF);
    float* su2 = (float*)(ws + SU2_OFF);
    int* cursors = (int*)(ws + CUR_OFF);
    int* lists = (int*)(ws + LIST_OFF);
    float* Wg = (float*)(ws + WG_OFF);

    hipLaunchKernelGGL(zero_cursors_kernel, dim3(1), dim3(64), 0, stream, cursors);
    hipLaunchKernelGGL(bucket_rank_kernel, dim3((NN + 255) / 256), dim3(256), 0, stream,
                       indices, cursors, lists);
    hipLaunchKernelGGL(sym_u_kernel, dim3((F3 * PP3 + F2 * PP2 + 255) / 256), dim3(256),
                       0, stream, u3, u2, su3, su2);
    hipLaunchKernelGGL(wprep_kernel, dim3(CC, EE), dim3(128), 0, stream,
                       su3, su2, u1, w3, w2, w1, Wg);
    hipLaunchKernelGGL(symcon_main_kernel, dim3(CC, EE, SPLIT), dim3(128), 0, stream,
                       x, Wg, cursors, lists, out);
}

// Round 3
// 131.937 us; speedup vs baseline: 2.8970x; 1.9961x over previous
//
#include <hip/hip_runtime.h>

// Problem constants (from reference)
#define NN 4096
#define CC 128
#define II 9
#define DD 9
#define EE 10
#define PP3 23
#define PP2 5
#define PP1 3
// symmetric monomial counts over 9 vars
#define F3 165   // i<=j<=k
#define F2 45    // i<=j
#define F1 9
#define FTOT (F3 + F2 + F1)  // 219
#define ROW 12               // padded row (floats), 48B -> float4-aligned
#define WIMG (FTOT * ROW)    // 2628 floats per (e,c) LDS image

// workspace layout (bytes)
#define SU3_ELEMS (F3 * PP3 * DD)              // 34155 floats
#define SU2_ELEMS (F2 * PP2 * DD)              // 2025 floats
#define SU3_OFF 0
#define SU2_OFF (SU3_OFF + SU3_ELEMS * 4)
#define CUR_OFF (SU2_OFF + SU2_ELEMS * 4)
#define LIST_OFF (CUR_OFF + 64)                // 16 ints + pad
#define WG_OFF (LIST_OFF + NN * EE * 4)        // then E*C*WIMG floats (~13.5 MB)

#define SPLIT 2

__global__ void zero_cursors_kernel(int* cursors) {
    if (threadIdx.x < 16) cursors[threadIdx.x] = 0;
}

// Atomic append bucketing. List ORDER is nondeterministic but each node's
// output is computed by a fixed FMA sequence independent of list position,
// so d_out is bit-deterministic.
__global__ void bucket_kernel(const int* __restrict__ indices,
                              int* __restrict__ cursors,
                              int* __restrict__ lists) {
    int b = blockIdx.x * blockDim.x + threadIdx.x;
    if (b < NN) {
        int e = indices[b];
        int slot = atomicAdd(&cursors[e], 1);
        lists[e * NN + slot] = b;
    }
}

// Symmetrize u3 over (i,j,k) and u2 over (i,j) into monomial-indexed tensors.
__global__ void sym_u_kernel(const float* __restrict__ u3,
                             const float* __restrict__ u2,
                             float* __restrict__ su3,
                             float* __restrict__ su2) {
    int gid = blockIdx.x * blockDim.x + threadIdx.x;
    if (gid < F3 * PP3) {
        int t = gid / PP3, p = gid % PP3;
        int I0 = 0, J0 = 0, K0 = 0, tt = 0;
        for (int i = 0; i < 9; i++)
            for (int j = i; j < 9; j++)
                for (int k = j; k < 9; k++) {
                    if (tt == t) { I0 = i; J0 = j; K0 = k; }
                    tt++;
                }
        int a[3] = {I0, J0, K0};
        const int ord[6][3] = {{0,1,2},{0,2,1},{1,0,2},{1,2,0},{2,0,1},{2,1,0}};
        int codes[6], pi[6], pj[6], pk[6];
        int np = 0;
        for (int q = 0; q < 6; q++) {
            int ii = a[ord[q][0]], jj = a[ord[q][1]], kk = a[ord[q][2]];
            int code = (ii * 9 + jj) * 9 + kk;
            bool seen = false;
            for (int r = 0; r < np; r++) if (codes[r] == code) seen = true;
            if (!seen) { codes[np] = code; pi[np] = ii; pj[np] = jj; pk[np] = kk; np++; }
        }
        for (int d = 0; d < 9; d++) {
            float s = 0.f;
            for (int q = 0; q < np; q++)
                s += u3[((((d * 9 + pi[q]) * 9 + pj[q]) * 9 + pk[q]) * PP3) + p];
            su3[(t * PP3 + p) * 9 + d] = s;
        }
    } else if (gid < F3 * PP3 + F2 * PP2) {
        int r = gid - F3 * PP3;
        int t = r / PP2, p = r % PP2;
        int I0 = 0, J0 = 0, tt = 0;
        for (int i = 0; i < 9; i++)
            for (int j = i; j < 9; j++) {
                if (tt == t) { I0 = i; J0 = j; }
                tt++;
            }
        for (int d = 0; d < 9; d++) {
            float s = u2[(((d * 9 + I0) * 9 + J0) * PP2) + p];
            if (I0 != J0) s += u2[(((d * 9 + J0) * 9 + I0) * PP2) + p];
            su2[(t * PP2 + p) * 9 + d] = s;
        }
    }
}

// Precompute the padded per-(e,c) weight image Wg[e][c][WIMG] so the main
// kernel's prologue is a pure coalesced float4 copy.
__global__ __launch_bounds__(128) void wprep_kernel(
    const float* __restrict__ su3,
    const float* __restrict__ su2,
    const float* __restrict__ u1,
    const float* __restrict__ w3,
    const float* __restrict__ w2,
    const float* __restrict__ w1,
    float* __restrict__ Wg)
{
    const int c = blockIdx.x;
    const int e = blockIdx.y;
    float* dst = Wg + (size_t)(e * CC + c) * WIMG;
    for (int idx = threadIdx.x; idx < WIMG; idx += blockDim.x) {
        int f = idx / ROW, r = idx % ROW;
        float v = 0.f;
        if (r < 9) {
            int d = r;
            if (f < F3) {
                for (int p = 0; p < PP3; p++)
                    v += su3[(f * PP3 + p) * 9 + d] * w3[(e * PP3 + p) * CC + c];
            } else if (f < F3 + F2) {
                int t = f - F3;
                for (int p = 0; p < PP2; p++)
                    v += su2[(t * PP2 + p) * 9 + d] * w2[(e * PP2 + p) * CC + c];
            } else {
                int i = f - F3 - F2;
                for (int p = 0; p < PP1; p++)
                    v += u1[(d * 9 + i) * PP1 + p] * w1[(e * PP1 + p) * CC + c];
            }
        }
        dst[idx] = v;
    }
}

// Main: grid (C, E, SPLIT). Copy W image to LDS, each thread evaluates the
// cubic form for TWO nodes simultaneously (18 FMA per 3 broadcast LDS reads).
__global__ __launch_bounds__(128, 4) void symcon_main_kernel(
    const float* __restrict__ x,
    const float* __restrict__ Wg,
    const int* __restrict__ cursors,
    const int* __restrict__ lists,
    float* __restrict__ out)
{
    const int c = blockIdx.x;
    const int e = blockIdx.y;
    const int s = blockIdx.z;
    __shared__ __align__(16) float sW[WIMG];

    const float4* wsrc = reinterpret_cast<const float4*>(Wg + (size_t)(e * CC + c) * WIMG);
    float4* wdst = reinterpret_cast<float4*>(sW);
    for (int q = threadIdx.x; q < WIMG / 4; q += blockDim.x) wdst[q] = wsrc[q];
    __syncthreads();

    const int cnt = cursors[e];
    const int chunk = (cnt + SPLIT - 1) / SPLIT;
    const int base = s * chunk;
    const int end = (base + chunk < cnt) ? (base + chunk) : cnt;

    for (int n0 = base + (int)threadIdx.x; n0 < end; n0 += 2 * (int)blockDim.x) {
        const int n1 = n0 + (int)blockDim.x;
        const bool has1 = (n1 < end);
        const int b0 = lists[e * NN + n0];
        const int b1 = has1 ? lists[e * NN + n1] : b0;

        float xv0[9], xv1[9];
        const float* xr0 = x + ((size_t)b0 * CC + c) * II;
        const float* xr1 = x + ((size_t)b1 * CC + c) * II;
        #pragma unroll
        for (int q = 0; q < 9; q++) {
            xv0[q] = xr0[q];
            xv1[q] = has1 ? xr1[q] : 0.f;
        }

        float a0[9], a1[9];
        #pragma unroll
        for (int d = 0; d < 9; d++) { a0[d] = 0.f; a1[d] = 0.f; }

        int f = 0;
        // degree 3: canonical i<=j<=k
        #pragma unroll 1
        for (int i = 0; i < 9; i++) {
            #pragma unroll 1
            for (int j = i; j < 9; j++) {
                float p0 = xv0[i] * xv0[j];
                float p1 = xv1[i] * xv1[j];
                for (int k = j; k < 9; k++) {
                    float m0 = p0 * xv0[k];
                    float m1 = p1 * xv1[k];
                    const float4* w4 = reinterpret_cast<const float4*>(&sW[f * ROW]);
                    float4 wa = w4[0];
                    float4 wb = w4[1];
                    float w8 = sW[f * ROW + 8];
                    a0[0] += wa.x * m0; a1[0] += wa.x * m1;
                    a0[1] += wa.y * m0; a1[1] += wa.y * m1;
                    a0[2] += wa.z * m0; a1[2] += wa.z * m1;
                    a0[3] += wa.w * m0; a1[3] += wa.w * m1;
                    a0[4] += wb.x * m0; a1[4] += wb.x * m1;
                    a0[5] += wb.y * m0; a1[5] += wb.y * m1;
                    a0[6] += wb.z * m0; a1[6] += wb.z * m1;
                    a0[7] += wb.w * m0; a1[7] += wb.w * m1;
                    a0[8] += w8 * m0;   a1[8] += w8 * m1;
                    f++;
                }
            }
        }
        // degree 2: canonical i<=j
        #pragma unroll 1
        for (int i = 0; i < 9; i++) {
            for (int j = i; j < 9; j++) {
                float m0 = xv0[i] * xv0[j];
                float m1 = xv1[i] * xv1[j];
                const float4* w4 = reinterpret_cast<const float4*>(&sW[f * ROW]);
                float4 wa = w4[0];
                float4 wb = w4[1];
                float w8 = sW[f * ROW + 8];
                a0[0] += wa.x * m0; a1[0] += wa.x * m1;
                a0[1] += wa.y * m0; a1[1] += wa.y * m1;
                a0[2] += wa.z * m0; a1[2] += wa.z * m1;
                a0[3] += wa.w * m0; a1[3] += wa.w * m1;
                a0[4] += wb.x * m0; a1[4] += wb.x * m1;
                a0[5] += wb.y * m0; a1[5] += wb.y * m1;
                a0[6] += wb.z * m0; a1[6] += wb.z * m1;
                a0[7] += wb.w * m0; a1[7] += wb.w * m1;
                a0[8] += w8 * m0;   a1[8] += w8 * m1;
                f++;
            }
        }
        // degree 1
        for (int i = 0; i < 9; i++) {
            float m0 = xv0[i];
            float m1 = xv1[i];
            const float4* w4 = reinterpret_cast<const float4*>(&sW[f * ROW]);
            float4 wa = w4[0];
            float4 wb = w4[1];
            float w8 = sW[f * ROW + 8];
            a0[0] += wa.x * m0; a1[0] += wa.x * m1;
            a0[1] += wa.y * m0; a1[1] += wa.y * m1;
            a0[2] += wa.z * m0; a1[2] += wa.z * m1;
            a0[3] += wa.w * m0; a1[3] += wa.w * m1;
            a0[4] += wb.x * m0; a1[4] += wb.x * m1;
            a0[5] += wb.y * m0; a1[5] += wb.y * m1;
            a0[6] += wb.z * m0; a1[6] += wb.z * m1;
            a0[7] += wb.w * m0; a1[7] += wb.w * m1;
            a0[8] += w8 * m0;   a1[8] += w8 * m1;
            f++;
        }

        float* op0 = out + ((size_t)b0 * CC + c) * DD;
        #pragma unroll
        for (int d = 0; d < 9; d++) op0[d] = a0[d];
        if (has1) {
            float* op1 = out + ((size_t)b1 * CC + c) * DD;
            #pragma unroll
            for (int d = 0; d < 9; d++) op1[d] = a1[d];
        }
    }
}

extern "C" void kernel_launch(void* const* d_in, const int* in_sizes, int n_in,
                              void* d_out, int out_size, void* d_ws, size_t ws_size,
                              hipStream_t stream) {
    const float* x   = (const float*)d_in[0];
    const int* indices = (const int*)d_in[1];
    const float* u3  = (const float*)d_in[2];
    const float* u2  = (const float*)d_in[3];
    const float* u1  = (const float*)d_in[4];
    const float* w3  = (const float*)d_in[5];
    const float* w2  = (const float*)d_in[6];
    const float* w1  = (const float*)d_in[7];
    float* out = (float*)d_out;

    char* ws = (char*)d_ws;
    float* su3 = (float*)(ws + SU3_OFF);
    float* su2 = (float*)(ws + SU2_OFF);
    int* cursors = (int*)(ws + CUR_OFF);
    int* lists = (int*)(ws + LIST_OFF);
    float* Wg = (float*)(ws + WG_OFF);

    hipLaunchKernelGGL(zero_cursors_kernel, dim3(1), dim3(64), 0, stream, cursors);
    hipLaunchKernelGGL(bucket_kernel, dim3((NN + 255) / 256), dim3(256), 0, stream,
                       indices, cursors, lists);
    hipLaunchKernelGGL(sym_u_kernel, dim3((F3 * PP3 + F2 * PP2 + 255) / 256), dim3(256),
                       0, stream, u3, u2, su3, su2);
    hipLaunchKernelGGL(wprep_kernel, dim3(CC, EE), dim3(128), 0, stream,
                       su3, su2, u1, w3, w2, w1, Wg);
    hipLaunchKernelGGL(symcon_main_kernel, dim3(CC, EE, SPLIT), dim3(128), 0, stream,
                       x, Wg, cursors, lists, out);
}